// Round 2
// baseline (727.913 us; speedup 1.0000x reference)
//
#include <hip/hip_runtime.h>

// ---------- types ----------
typedef _Float16 half8  __attribute__((ext_vector_type(8)));
typedef _Float16 half4v __attribute__((ext_vector_type(4)));
typedef _Float16 half2v __attribute__((ext_vector_type(2)));
typedef float    float4v __attribute__((ext_vector_type(4)));

__device__ __forceinline__ float hsig(float x) {
  return fminf(fmaxf(fmaf(x, 0.2f, 0.5f), 0.0f), 1.0f);
}

// ---------- prep: A-pair build: d1 = f16(src); d2 = f16(src) with cols j<2048 negated ----------
__global__ __launch_bounds__(256) void cvt_pair(const float* __restrict__ src,
                                                _Float16* __restrict__ d1,
                                                _Float16* __restrict__ d2) {
  int i = blockIdx.x * blockDim.x + threadIdx.x;   // 1,048,576 float4 groups
  int base = i * 4;
  int j = base & 4095;
  float s = (j < 2048) ? -1.0f : 1.0f;
  float4 v = *(const float4*)&src[base];
  half4v h1 = {(_Float16)v.x, (_Float16)v.y, (_Float16)v.z, (_Float16)v.w};
  half4v h2 = {(_Float16)(s * v.x), (_Float16)(s * v.y), (_Float16)(s * v.z), (_Float16)(s * v.w)};
  *(half4v*)&d1[base] = h1;
  *(half4v*)&d2[base] = h2;
}

// ---------- prep: transpose+cast the 4 raw weight matrices (2048 x 6144 f32) -> (6144 x 2048 f16) ----------
__global__ __launch_bounds__(256) void transpose_cast(
    const float* __restrict__ s0, const float* __restrict__ s1,
    const float* __restrict__ s2, const float* __restrict__ s3,
    _Float16* __restrict__ d0, _Float16* __restrict__ d1m,
    _Float16* __restrict__ d2m, _Float16* __restrict__ d3m)
{
  __shared__ float tile[64][65];
  const float* srcs[4] = {s0, s1, s2, s3};
  _Float16*    dsts[4] = {d0, d1m, d2m, d3m};
  const float* src = srcs[blockIdx.z];
  _Float16*    dst = dsts[blockIdx.z];

  const int tid = threadIdx.x;
  const int k0 = blockIdx.x * 64;   // 0..2047
  const int j0 = blockIdx.y * 64;   // 0..6143

  const int tx = tid & 63, ty = tid >> 6;
#pragma unroll
  for (int r = 0; r < 64; r += 4)
    tile[r + ty][tx] = src[(size_t)(k0 + r + ty) * 6144 + j0 + tx];   // tile[k][j]
  __syncthreads();

  const int txk = (tid & 31) * 2;
  const int tyn = tid >> 5;
#pragma unroll
  for (int r = 0; r < 64; r += 8) {
    int jl = r + tyn;
    half2v p = {(_Float16)tile[txk][jl], (_Float16)tile[txk + 1][jl]};
    *(half2v*)&dst[(size_t)(j0 + jl) * 2048 + k0 + txk] = p;
  }
}

// ---------- r-gate: p = hard_sigmoid(x_r)*h ; A1r = p ; A2r = (j<2048 ? -p : p) ----------
__global__ __launch_bounds__(256) void rgate(const _Float16* __restrict__ xacc,
                                             const float* __restrict__ h,
                                             _Float16* __restrict__ A1r,
                                             _Float16* __restrict__ A2r) {
  int i = blockIdx.x * blockDim.x + threadIdx.x;   // 1M float4 groups
  int base = i * 4;
  int m = base >> 12;
  int j = base & 4095;
  float s = (j < 2048) ? -1.0f : 1.0f;
  half4v rp = *(const half4v*)&xacc[(size_t)m * 12288 + 4096 + j];
  float4 hv = *(const float4*)&h[base];
  float p0 = hsig((float)rp[0]) * hv.x;
  float p1 = hsig((float)rp[1]) * hv.y;
  float p2 = hsig((float)rp[2]) * hv.z;
  float p3 = hsig((float)rp[3]) * hv.w;
  half4v o1 = {(_Float16)p0, (_Float16)p1, (_Float16)p2, (_Float16)p3};
  half4v o2 = {(_Float16)(s * p0), (_Float16)(s * p1), (_Float16)(s * p2), (_Float16)(s * p3)};
  *(half4v*)&A1r[base] = o1;
  *(half4v*)&A2r[base] = o2;
}

// ---------- m97-style GEMM: C[1024 x N] = A[1024 x 4096] * B, B stitched from WrT/WiT ----------
// For an N-tile in the "real" half (j<2048):  A=A1=[Xr|Xi], k<2048 from Wr, k>=2048 from Wi.
// For the "imag" half (j>=2048):              A=A2=[-Xr|Xi], k<2048 from Wi, k>=2048 from Wr.
// WrT/WiT are [6144][2048] f16 (row = gate*2048 + j', col = k').
// mode 0: xacc[m*12288+n] = f16(acc + bias(n))
// mode 1: xacc[m*12288+n] += acc
// mode 2: out[m*4096+n] = z*h + (1-z)*tanh(x_h + acc)
__global__ __launch_bounds__(256) void gemm_kernel(
    const _Float16* __restrict__ A1, const _Float16* __restrict__ A2,
    const _Float16* __restrict__ Wr, const _Float16* __restrict__ Wi,
    _Float16* __restrict__ xacc, float* __restrict__ out,
    const float* __restrict__ h_tm1,
    const float* __restrict__ rbias, const float* __restrict__ ibias,
    int mode)
{
  __shared__ __align__(16) _Float16 lds[16384];   // 32 KB: A tile [0,8192), B tile [8192,16384)
  const int tid  = threadIdx.x;
  const int lane = tid & 63;
  const int wave = tid >> 6;
  const int quad = lane >> 4;
  const int r16  = lane & 15;
  const int wm = (wave >> 1) * 64;
  const int wn = (wave & 1) * 64;
  const int mbase = blockIdx.y * 128;
  const int nbase = blockIdx.x * 128;

  const bool hi = (nbase & 2048) != 0;
  const _Float16* A   = hi ? A2 : A1;
  const _Float16* Blo = hi ? Wi : Wr;
  const _Float16* Bhi = hi ? Wr : Wi;
  const int browbase = (nbase >> 12) * 2048 + (nbase & 2047);

  float4v acc[4][4];
#pragma unroll
  for (int i = 0; i < 4; ++i)
#pragma unroll
    for (int j = 0; j < 4; ++j) acc[i][j] = (float4v){0.f, 0.f, 0.f, 0.f};

  // staging pointers: chunk c = i*256 + tid; 16B granules, XOR swizzle (slot ^ row&7)
  const _Float16* gpA[4];
  const _Float16* gpB[4];
  const _Float16* gpB2[4];
#pragma unroll
  for (int i = 0; i < 4; ++i) {
    int c = i * 256 + tid;
    int row = c >> 3;
    int sw = (c & 7) ^ (row & 7);
    gpA[i] = A + (size_t)(mbase + row) * 4096 + sw * 8;
    size_t ro = (size_t)(browbase + row) * 2048 + sw * 8;
    gpB[i]  = Blo + ro;
    gpB2[i] = Bhi + ro;
  }

  for (int h2 = 0; h2 < 2; ++h2) {
    for (int kk = 0; kk < 32; ++kk) {
#pragma unroll
      for (int i = 0; i < 4; ++i) {
        __builtin_amdgcn_global_load_lds(
            (__attribute__((address_space(1))) void*)gpA[i],
            (__attribute__((address_space(3))) void*)&lds[(i * 256 + tid) * 8],
            16, 0, 0);
        gpA[i] += 64;
      }
#pragma unroll
      for (int i = 0; i < 4; ++i) {
        __builtin_amdgcn_global_load_lds(
            (__attribute__((address_space(1))) void*)gpB[i],
            (__attribute__((address_space(3))) void*)&lds[8192 + (i * 256 + tid) * 8],
            16, 0, 0);
        gpB[i] += 64;
      }
      __syncthreads();
#pragma unroll
      for (int ks = 0; ks < 2; ++ks) {
        half8 af[4], bf[4];
#pragma unroll
        for (int t = 0; t < 4; ++t) {
          int akg = ks * 4 + quad;
          int arow = wm + t * 16 + r16;
          af[t] = *(const half8*)&lds[(arow * 8 + (akg ^ (arow & 7))) * 8];
          int brow = wn + t * 16 + r16;
          bf[t] = *(const half8*)&lds[8192 + (brow * 8 + (akg ^ (brow & 7))) * 8];
        }
#pragma unroll
        for (int mt = 0; mt < 4; ++mt)
#pragma unroll
          for (int nt = 0; nt < 4; ++nt)
            acc[mt][nt] = __builtin_amdgcn_mfma_f32_16x16x32_f16(af[mt], bf[nt], acc[mt][nt], 0, 0, 0);
      }
      __syncthreads();
    }
    if (h2 == 0) {
#pragma unroll
      for (int i = 0; i < 4; ++i) gpB[i] = gpB2[i];
    }
  }

  // epilogue: C/D layout col = lane&15, row = quad*4 + e
  const int mrow0 = mbase + wm + quad * 4;
  const int ncol0 = nbase + wn + r16;
  if (mode == 0) {
#pragma unroll
    for (int nt = 0; nt < 4; ++nt) {
      int n = ncol0 + nt * 16;
      int g = n >> 12, j = n & 4095;
      float b = (j < 2048) ? rbias[g * 2048 + j] : ibias[g * 2048 + j - 2048];
#pragma unroll
      for (int mt = 0; mt < 4; ++mt)
#pragma unroll
        for (int e = 0; e < 4; ++e) {
          int m = mrow0 + mt * 16 + e;
          xacc[(size_t)m * 12288 + n] = (_Float16)(acc[mt][nt][e] + b);
        }
    }
  } else if (mode == 1) {
#pragma unroll
    for (int nt = 0; nt < 4; ++nt) {
      int n = ncol0 + nt * 16;
#pragma unroll
      for (int mt = 0; mt < 4; ++mt)
#pragma unroll
        for (int e = 0; e < 4; ++e) {
          int m = mrow0 + mt * 16 + e;
          size_t idx = (size_t)m * 12288 + n;
          xacc[idx] = (_Float16)((float)xacc[idx] + acc[mt][nt][e]);
        }
    }
  } else {
#pragma unroll
    for (int nt = 0; nt < 4; ++nt) {
      int n = ncol0 + nt * 16;
#pragma unroll
      for (int mt = 0; mt < 4; ++mt)
#pragma unroll
        for (int e = 0; e < 4; ++e) {
          int m = mrow0 + mt * 16 + e;
          float z  = hsig((float)xacc[(size_t)m * 12288 + n]);
          float xh = (float)xacc[(size_t)m * 12288 + 8192 + n];
          float hh = tanhf(xh + acc[mt][nt][e]);
          float ht = h_tm1[(size_t)m * 4096 + n];
          out[(size_t)m * 4096 + n] = z * ht + (1.0f - z) * hh;
        }
    }
  }
}

// ---------- launch ----------
extern "C" void kernel_launch(void* const* d_in, const int* in_sizes, int n_in,
                              void* d_out, int out_size, void* d_ws, size_t ws_size,
                              hipStream_t stream) {
  const float* inputs = (const float*)d_in[0];
  const float* h_tm1  = (const float*)d_in[1];
  const float* rk     = (const float*)d_in[2];
  const float* ik     = (const float*)d_in[3];
  const float* rrk    = (const float*)d_in[4];
  const float* irk    = (const float*)d_in[5];
  const float* rb     = (const float*)d_in[6];
  const float* ib     = (const float*)d_in[7];
  float* out = (float*)d_out;

  char* ws = (char*)d_ws;
  // ws layout (bytes), total 159,383,552 (~152 MiB):
  _Float16* WrK  = (_Float16*)(ws + 0);           // 6144*2048*2 = 25,165,824
  _Float16* WiK  = (_Float16*)(ws + 25165824);
  _Float16* WrR  = (_Float16*)(ws + 50331648);
  _Float16* WiR  = (_Float16*)(ws + 75497472);
  _Float16* A1x  = (_Float16*)(ws + 100663296);   // 1024*4096*2 = 8,388,608
  _Float16* A2x  = (_Float16*)(ws + 109051904);
  _Float16* A1h  = (_Float16*)(ws + 117440512);
  _Float16* A2h  = (_Float16*)(ws + 125829120);
  _Float16* xacc = (_Float16*)(ws + 134217728);   // 1024*12288*2 = 25,165,824
  _Float16* A1r  = A1x;   // alias: inputs-f16 dead after GEMM1
  _Float16* A2r  = A2x;

  cvt_pair<<<4096, 256, 0, stream>>>(inputs, A1x, A2x);
  cvt_pair<<<4096, 256, 0, stream>>>(h_tm1, A1h, A2h);
  transpose_cast<<<dim3(32, 96, 4), 256, 0, stream>>>(rk, ik, rrk, irk, WrK, WiK, WrR, WiR);
  // x_{z,r,h} = X @ Kall + bias   (N = 12288)
  gemm_kernel<<<dim3(96, 8), 256, 0, stream>>>(A1x, A2x, WrK, WiK, xacc, nullptr, nullptr, rb, ib, 0);
  // += h @ R_{z,r}                (N = 8192)
  gemm_kernel<<<dim3(64, 8), 256, 0, stream>>>(A1h, A2h, WrR, WiR, xacc, nullptr, nullptr, nullptr, nullptr, 1);
  // rh = hard_sigmoid(x_r) * h_tm1  (both sign variants)
  rgate<<<4096, 256, 0, stream>>>(xacc, h_tm1, A1r, A2r);
  // h = z*h_tm1 + (1-z)*tanh(x_h + rh@Rh)   (N = 4096, gate-h weight rows, fused epilogue)
  gemm_kernel<<<dim3(32, 8), 256, 0, stream>>>(A1r, A2r, WrR + (size_t)4096 * 2048,
                                               WiR + (size_t)4096 * 2048, xacc, out, h_tm1,
                                               nullptr, nullptr, 2);
}

// Round 3
// 605.103 us; speedup vs baseline: 1.2030x; 1.2030x over previous
//
#include <hip/hip_runtime.h>

// ---------- types ----------
typedef _Float16 half8  __attribute__((ext_vector_type(8)));
typedef _Float16 half4v __attribute__((ext_vector_type(4)));
typedef _Float16 half2v __attribute__((ext_vector_type(2)));
typedef float    float4v __attribute__((ext_vector_type(4)));

__device__ __forceinline__ float hsig(float x) {
  return fminf(fmaxf(fmaf(x, 0.2f, 0.5f), 0.0f), 1.0f);
}

// ---------- prep: A-pair build: d1 = f16(src); d2 = f16(src) with cols j<2048 negated ----------
__global__ __launch_bounds__(256) void cvt_pair(const float* __restrict__ src,
                                                _Float16* __restrict__ d1,
                                                _Float16* __restrict__ d2) {
  int i = blockIdx.x * blockDim.x + threadIdx.x;   // 1,048,576 float4 groups
  int base = i * 4;
  int j = base & 4095;
  float s = (j < 2048) ? -1.0f : 1.0f;
  float4 v = *(const float4*)&src[base];
  half4v h1 = {(_Float16)v.x, (_Float16)v.y, (_Float16)v.z, (_Float16)v.w};
  half4v h2 = {(_Float16)(s * v.x), (_Float16)(s * v.y), (_Float16)(s * v.z), (_Float16)(s * v.w)};
  *(half4v*)&d1[base] = h1;
  *(half4v*)&d2[base] = h2;
}

// ---------- prep: transpose+cast the 4 raw weight matrices (2048 x 6144 f32) -> (6144 x 2048 f16) ----------
__global__ __launch_bounds__(256) void transpose_cast(
    const float* __restrict__ s0, const float* __restrict__ s1,
    const float* __restrict__ s2, const float* __restrict__ s3,
    _Float16* __restrict__ d0, _Float16* __restrict__ d1m,
    _Float16* __restrict__ d2m, _Float16* __restrict__ d3m)
{
  __shared__ float tile[64][65];
  const float* srcs[4] = {s0, s1, s2, s3};
  _Float16*    dsts[4] = {d0, d1m, d2m, d3m};
  const float* src = srcs[blockIdx.z];
  _Float16*    dst = dsts[blockIdx.z];

  const int tid = threadIdx.x;
  const int k0 = blockIdx.x * 64;   // 0..2047
  const int j0 = blockIdx.y * 64;   // 0..6143

  const int tx = tid & 63, ty = tid >> 6;
#pragma unroll
  for (int r = 0; r < 64; r += 4)
    tile[r + ty][tx] = src[(size_t)(k0 + r + ty) * 6144 + j0 + tx];   // tile[k][j]
  __syncthreads();

  const int txk = (tid & 31) * 2;
  const int tyn = tid >> 5;
#pragma unroll
  for (int r = 0; r < 64; r += 8) {
    int jl = r + tyn;
    half2v p = {(_Float16)tile[txk][jl], (_Float16)tile[txk + 1][jl]};
    *(half2v*)&dst[(size_t)(j0 + jl) * 2048 + k0 + txk] = p;
  }
}

// ---------- r-gate: p = hard_sigmoid(x_r)*h ; A1r = p ; A2r = (j<2048 ? -p : p) ----------
__global__ __launch_bounds__(256) void rgate(const _Float16* __restrict__ xacc,
                                             const float* __restrict__ h,
                                             _Float16* __restrict__ A1r,
                                             _Float16* __restrict__ A2r) {
  int i = blockIdx.x * blockDim.x + threadIdx.x;   // 1M float4 groups
  int base = i * 4;
  int m = base >> 12;
  int j = base & 4095;
  float s = (j < 2048) ? -1.0f : 1.0f;
  half4v rp = *(const half4v*)&xacc[(size_t)m * 12288 + 4096 + j];
  float4 hv = *(const float4*)&h[base];
  float p0 = hsig((float)rp[0]) * hv.x;
  float p1 = hsig((float)rp[1]) * hv.y;
  float p2 = hsig((float)rp[2]) * hv.z;
  float p3 = hsig((float)rp[3]) * hv.w;
  half4v o1 = {(_Float16)p0, (_Float16)p1, (_Float16)p2, (_Float16)p3};
  half4v o2 = {(_Float16)(s * p0), (_Float16)(s * p1), (_Float16)(s * p2), (_Float16)(s * p3)};
  *(half4v*)&A1r[base] = o1;
  *(half4v*)&A2r[base] = o2;
}

// ---------- fused GEMM: C[1024 x N] = A[1024 x Kp] * B stitched from WrT/WiT ----------
// 128x128 tile / block, 4 waves (2x2), 4x4 16x16x32 f16 MFMA frags per wave, BK=128.
// LDS 64 KB: A tile 128x128 [0,16384) elems, B tile [16384,32768), 16B granules
// XOR-swizzled (slot ^ (row&7)), 16 granules per row.
// K runs in phases of 2048 (16 iters each); phase switches A-half and B-matrix.
// FINAL=0: z,r gates K=8192 (X*K then H*R), h gate K=4096 (X*K); writes
//          xacc[m*12288+n] = f16(acc + bias).
// FINAL=1: K=4096 over Rh; out = z*h + (1-z)*tanh(x_h + acc).
template<int FINAL>
__global__ __launch_bounds__(256) void gemm_big(
    const _Float16* __restrict__ Ax1, const _Float16* __restrict__ Ax2,
    const _Float16* __restrict__ Ah1, const _Float16* __restrict__ Ah2,
    const _Float16* __restrict__ WKr, const _Float16* __restrict__ WKi,
    const _Float16* __restrict__ WRr, const _Float16* __restrict__ WRi,
    _Float16* __restrict__ xacc, float* __restrict__ out,
    const float* __restrict__ h_tm1,
    const float* __restrict__ rbias, const float* __restrict__ ibias)
{
  __shared__ __align__(16) _Float16 lds[32768];   // 64 KB
  const int tid  = threadIdx.x;
  const int lane = tid & 63;
  const int wave = tid >> 6;
  const int quad = lane >> 4;
  const int r16  = lane & 15;
  const int wm = (wave >> 1) * 64;
  const int wn = (wave & 1) * 64;
  const int mbase = blockIdx.y * 128;
  const int nbase = blockIdx.x * 128;

  const int  gate   = nbase >> 12;
  const bool hi     = (nbase & 2048) != 0;
  const int  jprime = nbase & 2047;
  const size_t browK = (size_t)(gate * 2048 + jprime) * 2048;

  int nph;
  const _Float16* pA[4];
  const _Float16* pB[4];
  if (FINAL) {
    nph = 2;
    const _Float16* Ax = hi ? Ax2 : Ax1;
    const _Float16* BL = hi ? WKi : WKr;   // caller passes Rh row base here
    const _Float16* BH = hi ? WKr : WKi;
    pA[0] = Ax + (size_t)mbase * 4096;      pB[0] = BL + (size_t)jprime * 2048;
    pA[1] = pA[0] + 2048;                   pB[1] = BH + (size_t)jprime * 2048;
  } else {
    const _Float16* Ax = hi ? Ax2 : Ax1;
    const _Float16* KL = hi ? WKi : WKr;
    const _Float16* KH = hi ? WKr : WKi;
    pA[0] = Ax + (size_t)mbase * 4096;      pB[0] = KL + browK;
    pA[1] = pA[0] + 2048;                   pB[1] = KH + browK;
    if (gate < 2) {
      nph = 4;
      const _Float16* Ah = hi ? Ah2 : Ah1;
      const _Float16* RL = hi ? WRi : WRr;
      const _Float16* RH = hi ? WRr : WRi;
      pA[2] = Ah + (size_t)mbase * 4096;    pB[2] = RL + browK;
      pA[3] = pA[2] + 2048;                 pB[3] = RH + browK;
    } else {
      nph = 2;
    }
  }

  float4v acc[4][4];
#pragma unroll
  for (int i = 0; i < 4; ++i)
#pragma unroll
    for (int j = 0; j < 4; ++j) acc[i][j] = (float4v){0.f, 0.f, 0.f, 0.f};

  // per-thread staging offsets (elements), loop-invariant
  int offA[8], offB[8], ldsA[8], ldsB[8];
#pragma unroll
  for (int i = 0; i < 8; ++i) {
    int c = i * 256 + tid;          // granule chunk 0..2047
    int row = c >> 4;               // 0..127
    int sw = (c & 15) ^ (row & 7);  // XOR swizzle within row
    offA[i] = row * 4096 + sw * 8;  // A row stride 4096 elems
    offB[i] = row * 2048 + sw * 8;  // B row stride 2048 elems
    ldsA[i] = c * 8;
    ldsB[i] = 16384 + c * 8;
  }

  for (int p = 0; p < nph; ++p) {
    const _Float16* Ab = pA[p];
    const _Float16* Bb = pB[p];
    for (int it = 0; it < 16; ++it) {
#pragma unroll
      for (int i = 0; i < 8; ++i)
        __builtin_amdgcn_global_load_lds(
            (__attribute__((address_space(1))) void*)(Ab + offA[i]),
            (__attribute__((address_space(3))) void*)&lds[ldsA[i]], 16, 0, 0);
#pragma unroll
      for (int i = 0; i < 8; ++i)
        __builtin_amdgcn_global_load_lds(
            (__attribute__((address_space(1))) void*)(Bb + offB[i]),
            (__attribute__((address_space(3))) void*)&lds[ldsB[i]], 16, 0, 0);
      Ab += 128;
      Bb += 128;
      __syncthreads();
#pragma unroll
      for (int ks = 0; ks < 4; ++ks) {
        half8 af[4], bf[4];
        int akg = ks * 4 + quad;
#pragma unroll
        for (int t = 0; t < 4; ++t) {
          int arow = wm + t * 16 + r16;
          af[t] = *(const half8*)&lds[(arow * 16 + (akg ^ (arow & 7))) * 8];
          int brow = wn + t * 16 + r16;
          bf[t] = *(const half8*)&lds[16384 + (brow * 16 + (akg ^ (brow & 7))) * 8];
        }
#pragma unroll
        for (int mt = 0; mt < 4; ++mt)
#pragma unroll
          for (int nt = 0; nt < 4; ++nt)
            acc[mt][nt] = __builtin_amdgcn_mfma_f32_16x16x32_f16(af[mt], bf[nt], acc[mt][nt], 0, 0, 0);
      }
      __syncthreads();
    }
  }

  // epilogue: C/D layout col = lane&15, row = quad*4 + e
  const int mrow0 = mbase + wm + quad * 4;
  const int ncol0 = nbase + wn + r16;
  if (!FINAL) {
#pragma unroll
    for (int nt = 0; nt < 4; ++nt) {
      int n = ncol0 + nt * 16;
      int g = n >> 12, j = n & 4095;
      float b = (j < 2048) ? rbias[g * 2048 + j] : ibias[g * 2048 + j - 2048];
#pragma unroll
      for (int mt = 0; mt < 4; ++mt)
#pragma unroll
        for (int e = 0; e < 4; ++e) {
          int m = mrow0 + mt * 16 + e;
          xacc[(size_t)m * 12288 + n] = (_Float16)(acc[mt][nt][e] + b);
        }
    }
  } else {
#pragma unroll
    for (int nt = 0; nt < 4; ++nt) {
      int n = ncol0 + nt * 16;
#pragma unroll
      for (int mt = 0; mt < 4; ++mt)
#pragma unroll
        for (int e = 0; e < 4; ++e) {
          int m = mrow0 + mt * 16 + e;
          float z  = hsig((float)xacc[(size_t)m * 12288 + n]);
          float xh = (float)xacc[(size_t)m * 12288 + 8192 + n];
          float hh = tanhf(xh + acc[mt][nt][e]);
          float ht = h_tm1[(size_t)m * 4096 + n];
          out[(size_t)m * 4096 + n] = z * ht + (1.0f - z) * hh;
        }
    }
  }
}

// ---------- launch ----------
extern "C" void kernel_launch(void* const* d_in, const int* in_sizes, int n_in,
                              void* d_out, int out_size, void* d_ws, size_t ws_size,
                              hipStream_t stream) {
  const float* inputs = (const float*)d_in[0];
  const float* h_tm1  = (const float*)d_in[1];
  const float* rk     = (const float*)d_in[2];
  const float* ik     = (const float*)d_in[3];
  const float* rrk    = (const float*)d_in[4];
  const float* irk    = (const float*)d_in[5];
  const float* rb     = (const float*)d_in[6];
  const float* ib     = (const float*)d_in[7];
  float* out = (float*)d_out;

  char* ws = (char*)d_ws;
  // ws layout (bytes), total 159,383,552 (~152 MiB):
  _Float16* WrK  = (_Float16*)(ws + 0);           // 6144*2048*2 = 25,165,824
  _Float16* WiK  = (_Float16*)(ws + 25165824);
  _Float16* WrR  = (_Float16*)(ws + 50331648);
  _Float16* WiR  = (_Float16*)(ws + 75497472);
  _Float16* A1x  = (_Float16*)(ws + 100663296);   // 1024*4096*2 = 8,388,608
  _Float16* A2x  = (_Float16*)(ws + 109051904);
  _Float16* A1h  = (_Float16*)(ws + 117440512);
  _Float16* A2h  = (_Float16*)(ws + 125829120);
  _Float16* xacc = (_Float16*)(ws + 134217728);   // 1024*12288*2 = 25,165,824
  _Float16* A1r  = A1x;   // alias: inputs-f16 dead after the fused GEMM
  _Float16* A2r  = A2x;

  cvt_pair<<<4096, 256, 0, stream>>>(inputs, A1x, A2x);
  cvt_pair<<<4096, 256, 0, stream>>>(h_tm1, A1h, A2h);
  transpose_cast<<<dim3(32, 96, 4), 256, 0, stream>>>(rk, ik, rrk, irk, WrK, WiK, WrR, WiR);
  // fused: x_z+h@Rz+bz, x_r+h@Rr+br (K=8192), x_h+bh (K=4096)  (N = 12288)
  gemm_big<0><<<dim3(96, 8), 256, 0, stream>>>(A1x, A2x, A1h, A2h, WrK, WiK, WrR, WiR,
                                               xacc, nullptr, nullptr, rb, ib);
  // rh = hard_sigmoid(x_r + h@Rr) * h_tm1  (both sign variants)
  rgate<<<4096, 256, 0, stream>>>(xacc, h_tm1, A1r, A2r);
  // h = z*h_tm1 + (1-z)*tanh(x_h + rh@Rh)   (N = 4096, Rh rows, fused epilogue)
  gemm_big<1><<<dim3(32, 8), 256, 0, stream>>>(A1r, A2r, nullptr, nullptr,
                                               WrR + (size_t)4096 * 2048,
                                               WiR + (size_t)4096 * 2048,
                                               nullptr, nullptr, xacc, out, h_tm1,
                                               nullptr, nullptr);
}

// Round 4
// 504.493 us; speedup vs baseline: 1.4429x; 1.1994x over previous
//
#include <hip/hip_runtime.h>

// ---------- types ----------
typedef _Float16 half8  __attribute__((ext_vector_type(8)));
typedef _Float16 half4v __attribute__((ext_vector_type(4)));
typedef _Float16 half2v __attribute__((ext_vector_type(2)));
typedef float    float4v __attribute__((ext_vector_type(4)));

__device__ __forceinline__ float hsig(float x) {
  return fminf(fmaxf(fmaf(x, 0.2f, 0.5f), 0.0f), 1.0f);
}

// ---------- prep: A-pair build: d1 = f16(src); d2 = f16(src) with cols j<2048 negated ----------
__global__ __launch_bounds__(256) void cvt_pair(const float* __restrict__ src,
                                                _Float16* __restrict__ d1,
                                                _Float16* __restrict__ d2) {
  int i = blockIdx.x * blockDim.x + threadIdx.x;   // 1,048,576 float4 groups
  int base = i * 4;
  int j = base & 4095;
  float s = (j < 2048) ? -1.0f : 1.0f;
  float4 v = *(const float4*)&src[base];
  half4v h1 = {(_Float16)v.x, (_Float16)v.y, (_Float16)v.z, (_Float16)v.w};
  half4v h2 = {(_Float16)(s * v.x), (_Float16)(s * v.y), (_Float16)(s * v.z), (_Float16)(s * v.w)};
  *(half4v*)&d1[base] = h1;
  *(half4v*)&d2[base] = h2;
}

// ---------- prep: transpose+cast the 4 raw weight matrices (2048 x 6144 f32) -> (6144 x 2048 f16) ----------
__global__ __launch_bounds__(256) void transpose_cast(
    const float* __restrict__ s0, const float* __restrict__ s1,
    const float* __restrict__ s2, const float* __restrict__ s3,
    _Float16* __restrict__ d0, _Float16* __restrict__ d1m,
    _Float16* __restrict__ d2m, _Float16* __restrict__ d3m)
{
  __shared__ float tile[64][65];
  const float* srcs[4] = {s0, s1, s2, s3};
  _Float16*    dsts[4] = {d0, d1m, d2m, d3m};
  const float* src = srcs[blockIdx.z];
  _Float16*    dst = dsts[blockIdx.z];

  const int tid = threadIdx.x;
  const int k0 = blockIdx.x * 64;   // 0..2047
  const int j0 = blockIdx.y * 64;   // 0..6143

  const int tx = tid & 63, ty = tid >> 6;
#pragma unroll
  for (int r = 0; r < 64; r += 4)
    tile[r + ty][tx] = src[(size_t)(k0 + r + ty) * 6144 + j0 + tx];   // tile[k][j]
  __syncthreads();

  const int txk = (tid & 31) * 2;
  const int tyn = tid >> 5;
#pragma unroll
  for (int r = 0; r < 64; r += 8) {
    int jl = r + tyn;
    half2v p = {(_Float16)tile[txk][jl], (_Float16)tile[txk + 1][jl]};
    *(half2v*)&dst[(size_t)(j0 + jl) * 2048 + k0 + txk] = p;
  }
}

// ---------- r-gate: p = hard_sigmoid(x_r)*h ; A1r = p ; A2r = (j<2048 ? -p : p) ----------
__global__ __launch_bounds__(256) void rgate(const _Float16* __restrict__ xacc,
                                             const float* __restrict__ h,
                                             _Float16* __restrict__ A1r,
                                             _Float16* __restrict__ A2r) {
  int i = blockIdx.x * blockDim.x + threadIdx.x;   // 1M float4 groups
  int base = i * 4;
  int m = base >> 12;
  int j = base & 4095;
  float s = (j < 2048) ? -1.0f : 1.0f;
  half4v rp = *(const half4v*)&xacc[(size_t)m * 12288 + 4096 + j];
  float4 hv = *(const float4*)&h[base];
  float p0 = hsig((float)rp[0]) * hv.x;
  float p1 = hsig((float)rp[1]) * hv.y;
  float p2 = hsig((float)rp[2]) * hv.z;
  float p3 = hsig((float)rp[3]) * hv.w;
  half4v o1 = {(_Float16)p0, (_Float16)p1, (_Float16)p2, (_Float16)p3};
  half4v o2 = {(_Float16)(s * p0), (_Float16)(s * p1), (_Float16)(s * p2), (_Float16)(s * p3)};
  *(half4v*)&A1r[base] = o1;
  *(half4v*)&A2r[base] = o2;
}

// ---------- combine: out = z*h + (1-z)*tanh(xh + P0 + P1) ----------
__global__ __launch_bounds__(256) void combine(const _Float16* __restrict__ xacc,
                                               const _Float16* __restrict__ P0,
                                               const _Float16* __restrict__ P1,
                                               const float* __restrict__ h,
                                               float* __restrict__ out) {
  int i = blockIdx.x * blockDim.x + threadIdx.x;   // 1M float4 groups
  int base = i * 4;
  int m = base >> 12;
  int j = base & 4095;
  half4v zv = *(const half4v*)&xacc[(size_t)m * 12288 + j];
  half4v xh = *(const half4v*)&xacc[(size_t)m * 12288 + 8192 + j];
  half4v p0 = *(const half4v*)&P0[base];
  half4v p1 = *(const half4v*)&P1[base];
  float4 hv = *(const float4*)&h[base];
  float4 o;
  {
    float z = hsig((float)zv[0]); float t = tanhf((float)xh[0] + (float)p0[0] + (float)p1[0]);
    o.x = z * hv.x + (1.0f - z) * t;
  }
  {
    float z = hsig((float)zv[1]); float t = tanhf((float)xh[1] + (float)p0[1] + (float)p1[1]);
    o.y = z * hv.y + (1.0f - z) * t;
  }
  {
    float z = hsig((float)zv[2]); float t = tanhf((float)xh[2] + (float)p0[2] + (float)p1[2]);
    o.z = z * hv.z + (1.0f - z) * t;
  }
  {
    float z = hsig((float)zv[3]); float t = tanhf((float)xh[3] + (float)p0[3] + (float)p1[3]);
    o.w = z * hv.w + (1.0f - z) * t;
  }
  *(float4*)&out[base] = o;
}

// ---------- fused GEMM: C[1024 x N] = A[1024 x Kp] * B stitched from WrT/WiT ----------
// 128x128 tile / block, 4 waves (2x2), 4x4 16x16x32 f16 MFMA frags per wave, BK=64.
// LDS 32 KB: A tile 128x64 [0,8192) elems, B tile [8192,16384). 16B granules,
// 8 per row, XOR-swizzled (slot ^ (row&7)) — measured conflict-free geometry (R2).
// K runs in phases of 2048 (32 iters each); phase switches A-half and B-matrix.
// FINAL=0: z,r gates K=8192 (X*K then H*R), h gate K=4096 (X*K);
//          writes xacc[m*12288+n] = f16(acc + bias). grid (96, 8).
// FINAL=1: split-K over Rh: blockIdx.z selects K-half; writes f16 partial to
//          P[z][m*4096+n]. grid (32, 8, 2).
template<int FINAL>
__global__ __launch_bounds__(256, 3) void gemm_big(
    const _Float16* __restrict__ Ax1, const _Float16* __restrict__ Ax2,
    const _Float16* __restrict__ Ah1, const _Float16* __restrict__ Ah2,
    const _Float16* __restrict__ WKr, const _Float16* __restrict__ WKi,
    const _Float16* __restrict__ WRr, const _Float16* __restrict__ WRi,
    _Float16* __restrict__ xacc,
    _Float16* __restrict__ P0, _Float16* __restrict__ P1,
    const float* __restrict__ rbias, const float* __restrict__ ibias)
{
  __shared__ __align__(16) _Float16 lds[16384];   // 32 KB
  const int tid  = threadIdx.x;
  const int lane = tid & 63;
  const int wave = tid >> 6;
  const int quad = lane >> 4;
  const int r16  = lane & 15;
  const int wm = (wave >> 1) * 64;
  const int wn = (wave & 1) * 64;
  const int mbase = blockIdx.y * 128;
  const int nbase = blockIdx.x * 128;

  const int  gate   = nbase >> 12;
  const bool hi     = (nbase & 2048) != 0;
  const int  jprime = nbase & 2047;

  int nph;
  const _Float16* pA[4];
  const _Float16* pB[4];
  if (FINAL) {
    nph = 1;
    const _Float16* Ax = hi ? Ax2 : Ax1;
    const _Float16* BL = hi ? WKi : WKr;   // caller passes Rh row bases in WK slots
    const _Float16* BH = hi ? WKr : WKi;
    if (blockIdx.z == 0) {
      pA[0] = Ax + (size_t)mbase * 4096;
      pB[0] = BL + (size_t)jprime * 2048;
    } else {
      pA[0] = Ax + (size_t)mbase * 4096 + 2048;
      pB[0] = BH + (size_t)jprime * 2048;
    }
  } else {
    const size_t browK = (size_t)(gate * 2048 + jprime) * 2048;
    const _Float16* Ax = hi ? Ax2 : Ax1;
    const _Float16* KL = hi ? WKi : WKr;
    const _Float16* KH = hi ? WKr : WKi;
    pA[0] = Ax + (size_t)mbase * 4096;      pB[0] = KL + browK;
    pA[1] = pA[0] + 2048;                   pB[1] = KH + browK;
    if (gate < 2) {
      nph = 4;
      const _Float16* Ah = hi ? Ah2 : Ah1;
      const _Float16* RL = hi ? WRi : WRr;
      const _Float16* RH = hi ? WRr : WRi;
      pA[2] = Ah + (size_t)mbase * 4096;    pB[2] = RL + browK;
      pA[3] = pA[2] + 2048;                 pB[3] = RH + browK;
    } else {
      nph = 2;
    }
  }

  float4v acc[4][4];
#pragma unroll
  for (int i = 0; i < 4; ++i)
#pragma unroll
    for (int j = 0; j < 4; ++j) acc[i][j] = (float4v){0.f, 0.f, 0.f, 0.f};

  // per-thread staging offsets (elements), loop-invariant.  BK=64: 8 granules/row.
  int offA[4], offB[4], ldsA[4], ldsB[4];
#pragma unroll
  for (int i = 0; i < 4; ++i) {
    int c = i * 256 + tid;          // granule chunk 0..1023
    int row = c >> 3;               // 0..127
    int sw = (c & 7) ^ (row & 7);   // XOR swizzle within row (R2 geometry, 0 conflicts)
    offA[i] = row * 4096 + sw * 8;  // A row stride 4096 elems
    offB[i] = row * 2048 + sw * 8;  // B row stride 2048 elems
    ldsA[i] = c * 8;
    ldsB[i] = 8192 + c * 8;
  }

#pragma unroll 1
  for (int p = 0; p < 4; ++p) {
    if (p >= nph) break;
    const _Float16* Ab = pA[p];
    const _Float16* Bb = pB[p];
#pragma unroll 1
    for (int it = 0; it < 32; ++it) {
#pragma unroll
      for (int i = 0; i < 4; ++i)
        __builtin_amdgcn_global_load_lds(
            (__attribute__((address_space(1))) void*)(Ab + offA[i]),
            (__attribute__((address_space(3))) void*)&lds[ldsA[i]], 16, 0, 0);
#pragma unroll
      for (int i = 0; i < 4; ++i)
        __builtin_amdgcn_global_load_lds(
            (__attribute__((address_space(1))) void*)(Bb + offB[i]),
            (__attribute__((address_space(3))) void*)&lds[ldsB[i]], 16, 0, 0);
      Ab += 64;
      Bb += 64;
      __syncthreads();
#pragma unroll
      for (int ks = 0; ks < 2; ++ks) {
        half8 af[4], bf[4];
        int akg = ks * 4 + quad;
#pragma unroll
        for (int t = 0; t < 4; ++t) {
          int arow = wm + t * 16 + r16;
          af[t] = *(const half8*)&lds[(arow * 8 + (akg ^ (arow & 7))) * 8];
          int brow = wn + t * 16 + r16;
          bf[t] = *(const half8*)&lds[8192 + (brow * 8 + (akg ^ (brow & 7))) * 8];
        }
#pragma unroll
        for (int mt = 0; mt < 4; ++mt)
#pragma unroll
          for (int nt = 0; nt < 4; ++nt)
            acc[mt][nt] = __builtin_amdgcn_mfma_f32_16x16x32_f16(af[mt], bf[nt], acc[mt][nt], 0, 0, 0);
      }
      __syncthreads();
    }
  }

  // epilogue: C/D layout col = lane&15, row = quad*4 + e
  const int mrow0 = mbase + wm + quad * 4;
  const int ncol0 = nbase + wn + r16;
  if (!FINAL) {
#pragma unroll
    for (int nt = 0; nt < 4; ++nt) {
      int n = ncol0 + nt * 16;
      int g = n >> 12, j = n & 4095;
      float b = (j < 2048) ? rbias[g * 2048 + j] : ibias[g * 2048 + j - 2048];
#pragma unroll
      for (int mt = 0; mt < 4; ++mt)
#pragma unroll
        for (int e = 0; e < 4; ++e) {
          int m = mrow0 + mt * 16 + e;
          xacc[(size_t)m * 12288 + n] = (_Float16)(acc[mt][nt][e] + b);
        }
    }
  } else {
    _Float16* P = blockIdx.z ? P1 : P0;
#pragma unroll
    for (int nt = 0; nt < 4; ++nt) {
      int n = ncol0 + nt * 16;
#pragma unroll
      for (int mt = 0; mt < 4; ++mt)
#pragma unroll
        for (int e = 0; e < 4; ++e) {
          int m = mrow0 + mt * 16 + e;
          P[(size_t)m * 4096 + n] = (_Float16)acc[mt][nt][e];
        }
    }
  }
}

// ---------- launch ----------
extern "C" void kernel_launch(void* const* d_in, const int* in_sizes, int n_in,
                              void* d_out, int out_size, void* d_ws, size_t ws_size,
                              hipStream_t stream) {
  const float* inputs = (const float*)d_in[0];
  const float* h_tm1  = (const float*)d_in[1];
  const float* rk     = (const float*)d_in[2];
  const float* ik     = (const float*)d_in[3];
  const float* rrk    = (const float*)d_in[4];
  const float* irk    = (const float*)d_in[5];
  const float* rb     = (const float*)d_in[6];
  const float* ib     = (const float*)d_in[7];
  float* out = (float*)d_out;

  char* ws = (char*)d_ws;
  // ws layout (bytes), total 159,383,552 (~152 MiB):
  _Float16* WrK  = (_Float16*)(ws + 0);           // 6144*2048*2 = 25,165,824
  _Float16* WiK  = (_Float16*)(ws + 25165824);
  _Float16* WrR  = (_Float16*)(ws + 50331648);
  _Float16* WiR  = (_Float16*)(ws + 75497472);
  _Float16* A1x  = (_Float16*)(ws + 100663296);   // 1024*4096*2 = 8,388,608
  _Float16* A2x  = (_Float16*)(ws + 109051904);
  _Float16* A1h  = (_Float16*)(ws + 117440512);
  _Float16* A2h  = (_Float16*)(ws + 125829120);
  _Float16* xacc = (_Float16*)(ws + 134217728);   // 1024*12288*2 = 25,165,824
  _Float16* A1r  = A1x;   // alias: inputs-f16 dead after the fused GEMM
  _Float16* A2r  = A2x;
  _Float16* P0   = A1h;   // alias: h-f16 dead after the fused GEMM
  _Float16* P1   = A2h;

  cvt_pair<<<4096, 256, 0, stream>>>(inputs, A1x, A2x);
  cvt_pair<<<4096, 256, 0, stream>>>(h_tm1, A1h, A2h);
  transpose_cast<<<dim3(32, 96, 4), 256, 0, stream>>>(rk, ik, rrk, irk, WrK, WiK, WrR, WiR);
  // fused: x_z+h@Rz+bz, x_r+h@Rr+br (K=8192), x_h+bh (K=4096)  (N = 12288)
  gemm_big<0><<<dim3(96, 8), 256, 0, stream>>>(A1x, A2x, A1h, A2h, WrK, WiK, WrR, WiR,
                                               xacc, nullptr, nullptr, rb, ib);
  // rh = hard_sigmoid(x_r + h@Rr) * h_tm1  (both sign variants)
  rgate<<<4096, 256, 0, stream>>>(xacc, h_tm1, A1r, A2r);
  // split-K partials of (r*h) @ Rh  (N = 4096, K halves -> P0/P1)
  gemm_big<1><<<dim3(32, 8, 2), 256, 0, stream>>>(A1r, A2r, nullptr, nullptr,
                                                  WrR + (size_t)4096 * 2048,
                                                  WiR + (size_t)4096 * 2048,
                                                  nullptr, nullptr, nullptr, P0, P1,
                                                  nullptr, nullptr);
  // h = z*h_tm1 + (1-z)*tanh(x_h + P0 + P1)
  combine<<<4096, 256, 0, stream>>>(xacc, P0, P1, h_tm1, out);
}